// Round 1
// 429.830 us; speedup vs baseline: 1.1701x; 1.1701x over previous
//
#include <hip/hip_runtime.h>
#include <math.h>

#define BATCH 32
#define SEQ   4096
#define DM    256
#define NS    64

// z-space recurrence: z = a*z + u, with x = B_tilde * z exactly.
// y = sum_n (C*B_tilde)[n] * z[n].  Removes the per-step bt*u multiply.
// chain = one (b,d) recurrence. 4 lanes per chain, 16 states per lane.
// wave = 64 lanes = 16 chains = (one b, 16 consecutive d).

__device__ __forceinline__ void load_a(const float* __restrict__ log_dt,
                                       const float* __restrict__ A_real,
                                       int d, int n0, float* a) {
    float dt = expf(log_dt[d]);  // DT_SCALE = 1.0
    const float* Ap = A_real + d * NS + n0;
#pragma unroll
    for (int k = 0; k < 16; ++k)
        a[k] = expf(Ap[k] * dt);
}

// Pass 1: local z-scan from zero per chunk; store end z-state into S[g].
__global__ __launch_bounds__(256, 8)
void pass1_kernel(const float* __restrict__ u,
                  const float* __restrict__ log_dt,
                  const float* __restrict__ A_real,
                  float* __restrict__ S, int Tc) {
    int wave = (blockIdx.x * blockDim.x + threadIdx.x) >> 6;
    int lane = threadIdx.x & 63;
    int wc = wave & 511;   // chain group
    int g  = wave >> 9;    // chunk
    int b  = wc >> 4;
    int d0 = (wc & 15) << 4;
    int c   = lane >> 2;   // chain within wave (0..15)
    int sub = lane & 3;    // lane within chain
    int d   = d0 + c;
    int n0  = sub << 4;

    float a[16], z[16];
    load_a(log_dt, A_real, d, n0, a);
#pragma unroll
    for (int k = 0; k < 16; ++k) z[k] = 0.0f;

    int t0 = g * Tc;
    int tl = lane >> 4;  // which of 4 time steps this lane loads
    const float* ubase = u + (size_t)b * SEQ * DM + d0 + (lane & 15);

    float ucur = ubase[(size_t)(t0 + tl) * DM];
    for (int t4 = 0; t4 < Tc; t4 += 4) {
        int tn = (t4 + 4 < Tc) ? (t0 + t4 + 4 + tl) : (t0 + tl);  // dummy-safe
        float unext = ubase[(size_t)tn * DM];
#pragma unroll
        for (int s = 0; s < 4; ++s) {
            float uv = __shfl(ucur, (s << 4) + c);
#pragma unroll
            for (int k = 0; k < 16; ++k)
                z[k] = fmaf(a[k], z[k], uv);   // single FMA per state
        }
        ucur = unext;
    }

    float* Sp = S + (((size_t)g * BATCH + b) * DM + d) * NS + n0;
    float4* Sp4 = (float4*)Sp;
#pragma unroll
    for (int j = 0; j < 4; ++j)
        Sp4[j] = make_float4(z[4 * j], z[4 * j + 1], z[4 * j + 2], z[4 * j + 3]);
}

// Pass 2: sequential chunk combine in z-space, in place. After this, S[g]
// holds the true initial z-state for chunk g (z0[0] = x0 / B_tilde, guarded).
__global__ void pass2_kernel(float* __restrict__ S,
                             const float* __restrict__ log_dt,
                             const float* __restrict__ A_real,
                             const float* __restrict__ B,
                             const float* __restrict__ x0,
                             int C, int Tc) {
    int idx = blockIdx.x * blockDim.x + threadIdx.x;  // b*16384 + d*64 + n
    if (idx >= BATCH * DM * NS) return;
    int dn = idx & (DM * NS - 1);
    int d = dn >> 6;
    float ar = A_real[dn];
    float dt = expf(log_dt[d]);
    float aT = expf(ar * dt * (float)Tc);  // a^Tc
    float x0v = x0[dn];
    float prev;
    if (x0v == 0.0f) {
        prev = 0.0f;                       // common/bench case
    } else {
        float at = expf(ar * dt);
        float bt = (1.0f - at) * B[dn] / ar;
        prev = (bt != 0.0f) ? (x0v / bt) : 0.0f;
    }
    for (int g = 0; g < C; ++g) {
        float* p = S + (size_t)g * (BATCH * DM * NS) + idx;
        float s = *p;
        *p = prev;
        prev = fmaf(aT, prev, s);
    }
}

// Pass 3: full z-scan per chunk from S[g], emit y = dot(cbt, z) every step.
__global__ __launch_bounds__(256, 6)
void pass3_kernel(const float* __restrict__ u,
                  const float* __restrict__ log_dt,
                  const float* __restrict__ A_real,
                  const float* __restrict__ B,
                  const float* __restrict__ Cm,
                  const float* __restrict__ S,
                  const float* __restrict__ x0,
                  float* __restrict__ y, int Tc, int useS) {
    int wave = (blockIdx.x * blockDim.x + threadIdx.x) >> 6;
    int lane = threadIdx.x & 63;
    int wc = wave & 511;
    int g  = wave >> 9;
    int b  = wc >> 4;
    int d0 = (wc & 15) << 4;
    int c   = lane >> 2;
    int sub = lane & 3;
    int d   = d0 + c;
    int n0  = sub << 4;

    float a[16], cbt[16], z[16];
    {
        float dt = expf(log_dt[d]);
        const float* Ap = A_real + d * NS + n0;
        const float* Bp = B + d * NS + n0;
        const float* Cp = Cm + d * NS + n0;
#pragma unroll
        for (int k = 0; k < 16; ++k) {
            float ar = Ap[k];
            float at = expf(ar * dt);
            a[k] = at;
            cbt[k] = Cp[k] * ((1.0f - at) * Bp[k] / ar);  // C * B_tilde
        }
        if (useS) {
            const float4* Sp4 = (const float4*)(S +
                (((size_t)g * BATCH + b) * DM + d) * NS + n0);
#pragma unroll
            for (int j = 0; j < 4; ++j) {
                float4 v = Sp4[j];
                z[4 * j] = v.x; z[4 * j + 1] = v.y;
                z[4 * j + 2] = v.z; z[4 * j + 3] = v.w;
            }
        } else {
            const float* Xp = x0 + d * NS + n0;
            const float* Bp2 = B + d * NS + n0;
#pragma unroll
            for (int k = 0; k < 16; ++k) {
                float x0v = Xp[k];
                if (x0v == 0.0f) { z[k] = 0.0f; }
                else {
                    float bt = (1.0f - a[k]) * Bp2[k] / (A_real + d * NS + n0)[k];
                    z[k] = (bt != 0.0f) ? (x0v / bt) : 0.0f;
                }
            }
        }
    }

    int t0 = g * Tc;
    int tl = lane >> 4;
    const float* ubase = u + (size_t)b * SEQ * DM + d0 + (lane & 15);
    float* ybase = y + (size_t)b * SEQ * DM + d;  // only sub==0 stores

    float ucur = ubase[(size_t)(t0 + tl) * DM];
    for (int t4 = 0; t4 < Tc; t4 += 4) {
        int tn = (t4 + 4 < Tc) ? (t0 + t4 + 4 + tl) : (t0 + tl);
        float unext = ubase[(size_t)tn * DM];
#pragma unroll
        for (int s = 0; s < 4; ++s) {
            float uv = __shfl(ucur, (s << 4) + c);
            float p0 = 0.0f, p1 = 0.0f;   // split the serial dot chain
#pragma unroll
            for (int k = 0; k < 16; k += 2) {
                z[k] = fmaf(a[k], z[k], uv);
                p0 = fmaf(cbt[k], z[k], p0);
                z[k + 1] = fmaf(a[k + 1], z[k + 1], uv);
                p1 = fmaf(cbt[k + 1], z[k + 1], p1);
            }
            float p = p0 + p1;
            p += __shfl_xor(p, 1);
            p += __shfl_xor(p, 2);
            if (sub == 0)
                ybase[(size_t)(t0 + t4 + s) * DM] = p;
        }
        ucur = unext;
    }
}

extern "C" void kernel_launch(void* const* d_in, const int* in_sizes, int n_in,
                              void* d_out, int out_size, void* d_ws, size_t ws_size,
                              hipStream_t stream) {
    const float* u      = (const float*)d_in[0];
    const float* log_dt = (const float*)d_in[1];
    const float* A_real = (const float*)d_in[2];
    const float* B      = (const float*)d_in[3];
    const float* Cm     = (const float*)d_in[4];
    const float* x0     = (const float*)d_in[5];
    float* y = (float*)d_out;
    float* S = (float*)d_ws;

    const size_t per_chunk = (size_t)BATCH * DM * NS * sizeof(float);  // 2 MB
    int C = 16;  // 16 chunks -> 8192 waves -> 32 waves/CU available
    while (C > 1 && (size_t)C * per_chunk > ws_size) C >>= 1;
    if ((size_t)C * per_chunk > ws_size) C = 1;
    int Tc = SEQ / C;

    if (C > 1) {
        pass1_kernel<<<dim3(C * 128), dim3(256), 0, stream>>>(
            u, log_dt, A_real, S, Tc);
        pass2_kernel<<<dim3((BATCH * DM * NS) / 256), dim3(256), 0, stream>>>(
            S, log_dt, A_real, B, x0, C, Tc);
    }
    pass3_kernel<<<dim3(C * 128), dim3(256), 0, stream>>>(
        u, log_dt, A_real, B, Cm, S, x0, y, Tc, (C > 1) ? 1 : 0);
}